// Round 1
// baseline (464.659 us; speedup 1.0000x reference)
//
#include <hip/hip_runtime.h>
#include <math.h>

#define NNODES 50000
#define NEDGES 800000
#define TE 64
#define NBASIS 10
#define RCUT 3.0f

__global__ __launch_bounds__(256) void zero_kernel(float4* __restrict__ out, int n4) {
    int i = blockIdx.x * blockDim.x + threadIdx.x;
    if (i < n4) out[i] = make_float4(0.f, 0.f, 0.f, 0.f);
}

__global__ __launch_bounds__(256) void edge_kernel(
    const float* __restrict__ pos, const float* __restrict__ x,
    const float* __restrict__ W1, const float* __restrict__ W2,
    const int* __restrict__ esrc, const int* __restrict__ edst,
    float* __restrict__ out)
{
    // u_buf: first hT[100][64] (6400 f), then reused as wl[64][128] (8192 f)
    __shared__ __align__(16) float u_buf[8192];
    __shared__ float embT[NBASIS * TE];      // [j][e]
    __shared__ float W1s[NBASIS * 100];      // [j][k]
    __shared__ float unit_l[TE][3];
    __shared__ int   src_l[TE];
    __shared__ int   dst_l[TE];
    __shared__ int   act_l[TE];

    const int t  = threadIdx.x;
    const int e0 = blockIdx.x * TE;

    // stage W1 (4 KB)
    for (int idx = t; idx < NBASIS * 100; idx += 256) W1s[idx] = W1[idx];

    // ---- Phase A1: geometry + radial embedding (threads 0..63, one edge each)
    if (t < TE) {
        int e = e0 + t;
        int s = esrc[e], d = edst[e];
        src_l[t] = s; dst_l[t] = d;
        float ax = pos[3*s], ay = pos[3*s+1], az = pos[3*s+2];
        float bx = pos[3*d], by = pos[3*d+1], bz = pos[3*d+2];
        float vx = ax - bx, vy = ay - by, vz = az - bz;
        float r = sqrtf(vx*vx + vy*vy + vz*vz + 1e-12f);
        float inv = 1.0f / r;
        unit_l[t][0] = vx * inv; unit_l[t][1] = vy * inv; unit_l[t][2] = vz * inv;
        int act = (r <= RCUT) ? 1 : 0;
        act_l[t] = act;
        const float step  = 2.0f / 9.0f;
        const float istep = 4.5f;                 // 1/step
        const float cemb  = 2.8231868f;           // sqrt(10)/1.12
        #pragma unroll
        for (int j = 0; j < NBASIS; ++j) {
            float dv = (r - (float)j * step) * istep;
            float ej = act ? (__expf(-dv * dv) * cemb) : 0.0f;
            embT[j * TE + t] = ej;
        }
    }
    __syncthreads();

    // ---- Phase A2: h = silu(emb @ W1 / sqrt(10)) -> u_buf as hT[k][e]
    {
        int e  = t & 63;
        int kg = t >> 6;                          // 4 groups x 25 k each
        float em[NBASIS];
        #pragma unroll
        for (int j = 0; j < NBASIS; ++j) em[j] = embT[j * TE + e];
        const float s10 = 0.31622776601683794f;   // 1/sqrt(10)
        for (int kk = 0; kk < 25; ++kk) {
            int k = kg * 25 + kk;
            float pre = 0.f;
            #pragma unroll
            for (int j = 0; j < NBASIS; ++j) pre += em[j] * W1s[j * 100 + k];
            float z = pre * s10;
            float h = z / (1.0f + __expf(-z));    // silu
            u_buf[k * TE + e] = h;
        }
    }
    __syncthreads();

    // ---- Phase B: w = h @ W2 / 10 ; thread = (eg: 8 edges, mg: 4 cols)
    float acc[8][4];
    {
        int mg = t & 31;
        int eg = t >> 5;
        #pragma unroll
        for (int a = 0; a < 8; ++a)
            #pragma unroll
            for (int b = 0; b < 4; ++b) acc[a][b] = 0.f;
        const float* w2p = W2 + mg * 4;
        const float* hb0 = u_buf + eg * 8;
        #pragma unroll 2
        for (int k = 0; k < 100; ++k) {
            float4 wv = *(const float4*)(w2p + (size_t)k * 128);
            float4 ha = *(const float4*)(hb0 + k * 64);
            float4 hc = *(const float4*)(hb0 + k * 64 + 4);
            float hh[8] = {ha.x, ha.y, ha.z, ha.w, hc.x, hc.y, hc.z, hc.w};
            float ww[4] = {wv.x, wv.y, wv.z, wv.w};
            #pragma unroll
            for (int a = 0; a < 8; ++a)
                #pragma unroll
                for (int b = 0; b < 4; ++b)
                    acc[a][b] += hh[a] * ww[b];
        }
    }
    __syncthreads();   // all hT reads done before overwriting u_buf with wl
    {
        int mg = t & 31;
        int eg = t >> 5;
        #pragma unroll
        for (int a = 0; a < 8; ++a) {
            float4 v = make_float4(acc[a][0] * 0.1f, acc[a][1] * 0.1f,
                                   acc[a][2] * 0.1f, acc[a][3] * 0.1f);
            *(float4*)(u_buf + (size_t)(eg * 8 + a) * 128 + mg * 4) = v;
        }
    }
    __syncthreads();

    // ---- Phase C: edge_feat + atomic scatter (256 outputs per edge, f = t)
    const int f = t;
    int cat, uu, ii = 0;
    if (f < 32)       { cat = 0; uu = f; }
    else if (f < 64)  { cat = 1; uu = f - 32; }
    else if (f < 160) { int g = f - 64;  cat = 2; uu = g / 3; ii = g - 3 * uu; }
    else              { int g = f - 160; cat = 3; uu = g / 3; ii = g - 3 * uu; }

    const float SQRT3 = 1.7320508075688772f;
    for (int e = 0; e < TE; ++e) {
        if (!act_l[e]) continue;
        const float* xr = x + (size_t)src_l[e] * 128;
        float* orow = out + (size_t)dst_l[e] * 256;
        const float* we = u_buf + (size_t)e * 128;
        float val;
        if (cat == 0) {
            val = we[uu] * xr[uu];
        } else if (cat == 1) {
            float dotv = xr[32 + 3*uu]     * unit_l[e][0]
                       + xr[32 + 3*uu + 1] * unit_l[e][1]
                       + xr[32 + 3*uu + 2] * unit_l[e][2];
            val = we[96 + uu] * dotv;
        } else if (cat == 2) {
            val = we[32 + uu] * xr[uu] * (SQRT3 * unit_l[e][ii]);
        } else {
            val = we[64 + uu] * xr[32 + 3*uu + ii];
        }
        atomicAdd(orow + f, val * 0.25f);   // / sqrt(16)
    }
}

extern "C" void kernel_launch(void* const* d_in, const int* in_sizes, int n_in,
                              void* d_out, int out_size, void* d_ws, size_t ws_size,
                              hipStream_t stream) {
    const float* pos = (const float*)d_in[0];
    const float* x   = (const float*)d_in[1];
    const float* W1  = (const float*)d_in[2];
    const float* W2  = (const float*)d_in[3];
    const int* esrc  = (const int*)d_in[4];
    const int* edst  = (const int*)d_in[5];
    float* out = (float*)d_out;

    int n4 = out_size / 4;  // out_size = 50000*256, divisible by 4
    zero_kernel<<<(n4 + 255) / 256, 256, 0, stream>>>((float4*)out, n4);

    int nblocks = (NEDGES + TE - 1) / TE;   // 12500
    edge_kernel<<<nblocks, 256, 0, stream>>>(pos, x, W1, W2, esrc, edst, out);
}

// Round 2
// 381.989 us; speedup vs baseline: 1.2164x; 1.2164x over previous
//
#include <hip/hip_runtime.h>
#include <math.h>

#define NNODES 50000
#define NEDGES 800000
#define TE 64
#define NBASIS 10
#define NT 2048
#define RCUT 3.0f

// ws layout:
//   [0, 1 MB)            : w-table  float[NT*128]
//   [1 MB, +16)          : active-edge counter (int)
//   [1 MB+16, +3.2 MB)   : compacted edge-id list int[NEDGES]

__global__ __launch_bounds__(256) void zero_out_kernel(float4* __restrict__ out, int n4) {
    int i = blockIdx.x * blockDim.x + threadIdx.x;
    if (i < n4) out[i] = make_float4(0.f, 0.f, 0.f, 0.f);
}

__global__ void zero_cnt_kernel(int* c) { if (threadIdx.x == 0) *c = 0; }

// ---- build w(r) lookup table: one block per r-point, 128 threads
__global__ __launch_bounds__(128) void table_kernel(
    const float* __restrict__ W1, const float* __restrict__ W2,
    float* __restrict__ tab)
{
    __shared__ float hs[100];
    const int i = blockIdx.x;
    const int t = threadIdx.x;
    const float r = (float)i * (RCUT / (float)(NT - 1));
    if (t < 100) {
        const float step  = 2.0f / 9.0f;
        const float istep = 4.5f;
        const float cemb  = 2.8234622f;          // sqrt(10)/1.12
        float pre = 0.f;
        #pragma unroll
        for (int j = 0; j < NBASIS; ++j) {
            float dv = (r - (float)j * step) * istep;
            float em = expf(-dv * dv) * cemb;
            pre += em * W1[j * 100 + t];
        }
        float z = pre * 0.316227766f;            // 1/sqrt(10)
        hs[t] = z / (1.0f + expf(-z));           // silu
    }
    __syncthreads();
    float acc = 0.f;
    for (int k = 0; k < 100; ++k)
        acc += hs[k] * W2[k * 128 + t];
    tab[i * 128 + t] = acc * 0.1f;               // / sqrt(100)
}

// ---- compact active edges (r <= RCUT), wave-aggregated atomics
__global__ __launch_bounds__(256) void compact_kernel(
    const float* __restrict__ pos,
    const int* __restrict__ esrc, const int* __restrict__ edst,
    int* __restrict__ cnt, int* __restrict__ elist)
{
    int e = blockIdx.x * 256 + threadIdx.x;
    bool act = false;
    if (e < NEDGES) {
        int s = esrc[e], d = edst[e];
        float vx = pos[3*s]   - pos[3*d];
        float vy = pos[3*s+1] - pos[3*d+1];
        float vz = pos[3*s+2] - pos[3*d+2];
        act = (vx*vx + vy*vy + vz*vz) <= RCUT * RCUT;
    }
    unsigned long long mask = __ballot(act);
    if (mask == 0ull) return;
    int lid = threadIdx.x & 63;
    int nbelow = __popcll(mask & ((1ull << lid) - 1ull));
    int leader = __ffsll((long long)mask) - 1;
    int base = 0;
    if (lid == leader) base = atomicAdd(cnt, __popcll(mask));
    base = __shfl(base, leader, 64);
    if (act) elist[base + nbelow] = e;
}

// ---- main scatter: 64 active edges per block
__global__ __launch_bounds__(256) void scatter_kernel(
    const float* __restrict__ pos, const float* __restrict__ x,
    const float* __restrict__ tab,
    const int* __restrict__ esrc, const int* __restrict__ edst,
    const int* __restrict__ cnt, const int* __restrict__ elist,
    float* __restrict__ out)
{
    __shared__ __align__(16) float wl[TE * 128];   // 32 KB
    __shared__ float unit_l[TE][3];
    __shared__ int   src_l[TE];
    __shared__ int   dst_l[TE];
    __shared__ int   ii_l[TE];
    __shared__ float fr_l[TE];

    const int t = threadIdx.x;
    const int n = *cnt;
    const int b0 = blockIdx.x * TE;
    if (b0 >= n) return;
    const int nloc = min(TE, n - b0);

    // Phase A: geometry + table coords (threads 0..63)
    if (t < TE && t < nloc) {
        int e = elist[b0 + t];
        int s = esrc[e], d = edst[e];
        src_l[t] = s; dst_l[t] = d;
        float vx = pos[3*s]   - pos[3*d];
        float vy = pos[3*s+1] - pos[3*d+1];
        float vz = pos[3*s+2] - pos[3*d+2];
        float r = sqrtf(vx*vx + vy*vy + vz*vz + 1e-12f);
        float inv = 1.0f / r;
        unit_l[t][0] = vx * inv; unit_l[t][1] = vy * inv; unit_l[t][2] = vz * inv;
        const float iscale = (float)(NT - 1) / RCUT;
        float fidx = r * iscale;
        int ii = (int)fidx;
        ii = min(ii, NT - 2);
        ii_l[t] = ii;
        fr_l[t] = fidx - (float)ii;
    }
    __syncthreads();

    // Phase B: interpolate w rows into LDS (coalesced table reads)
    #pragma unroll 4
    for (int it = 0; it < 32; ++it) {
        int idx = t + it * 256;
        int e = idx >> 7, m = idx & 127;
        if (e < nloc) {
            int ii = ii_l[e];
            float fr = fr_l[e];
            float a = tab[ii * 128 + m];
            float b = tab[ii * 128 + 128 + m];
            wl[idx] = a + (b - a) * fr;
        }
    }
    __syncthreads();

    // Phase C: edge_feat + atomic scatter (f = t, 256 outputs/edge)
    const int f = t;
    int cat, uu, ii2 = 0;
    if (f < 32)       { cat = 0; uu = f; }
    else if (f < 64)  { cat = 1; uu = f - 32; }
    else if (f < 160) { int g = f - 64;  cat = 2; uu = g / 3; ii2 = g - 3 * uu; }
    else              { int g = f - 160; cat = 3; uu = g / 3; ii2 = g - 3 * uu; }

    const float SQRT3 = 1.7320508075688772f;
    for (int e = 0; e < nloc; ++e) {
        const float* xr = x + (size_t)src_l[e] * 128;
        float* orow = out + (size_t)dst_l[e] * 256;
        const float* we = wl + (size_t)e * 128;
        float val;
        if (cat == 0) {
            val = we[uu] * xr[uu];
        } else if (cat == 1) {
            float dotv = xr[32 + 3*uu]     * unit_l[e][0]
                       + xr[32 + 3*uu + 1] * unit_l[e][1]
                       + xr[32 + 3*uu + 2] * unit_l[e][2];
            val = we[96 + uu] * dotv;
        } else if (cat == 2) {
            val = we[32 + uu] * xr[uu] * (SQRT3 * unit_l[e][ii2]);
        } else {
            val = we[64 + uu] * xr[32 + 3*uu + ii2];
        }
        atomicAdd(orow + f, val * 0.25f);   // / sqrt(16)
    }
}

extern "C" void kernel_launch(void* const* d_in, const int* in_sizes, int n_in,
                              void* d_out, int out_size, void* d_ws, size_t ws_size,
                              hipStream_t stream) {
    const float* pos = (const float*)d_in[0];
    const float* x   = (const float*)d_in[1];
    const float* W1  = (const float*)d_in[2];
    const float* W2  = (const float*)d_in[3];
    const int* esrc  = (const int*)d_in[4];
    const int* edst  = (const int*)d_in[5];
    float* out = (float*)d_out;

    char* wsb = (char*)d_ws;
    float* tab  = (float*)wsb;                         // 1 MB
    int*   cnt  = (int*)(wsb + (1 << 20));             // 16 B
    int*   elist= (int*)(wsb + (1 << 20) + 16);        // 3.2 MB

    zero_cnt_kernel<<<1, 64, 0, stream>>>(cnt);
    int n4 = out_size / 4;
    zero_out_kernel<<<(n4 + 255) / 256, 256, 0, stream>>>((float4*)out, n4);
    table_kernel<<<NT, 128, 0, stream>>>(W1, W2, tab);
    compact_kernel<<<(NEDGES + 255) / 256, 256, 0, stream>>>(pos, esrc, edst, cnt, elist);

    int nblocks = (NEDGES + TE - 1) / TE;   // worst-case grid; early-exit on cnt
    scatter_kernel<<<nblocks, 256, 0, stream>>>(pos, x, tab, esrc, edst, cnt, elist, out);
}

// Round 3
// 171.428 us; speedup vs baseline: 2.7105x; 2.2283x over previous
//
#include <hip/hip_runtime.h>
#include <math.h>

#define NNODES 50000
#define NEDGES 800000
#define NBASIS 10
#define NT 2048
#define RCUT 3.0f
#define NCHUNK 196   // ceil(50000/256)

// ws layout (bytes):
//   tab      @ 0         : float[NT*128]        (1 MB)
//   hist     @ 0x100000  : int[50000]
//   row_st   @ 0x140000  : int[50001]
//   cursor   @ 0x180000  : int[50000]
//   bsums    @ 0x1C0000  : int[256]
//   bscan    @ 0x1C1000  : int[256]
//   actbits  @ 0x200000  : ull[12500]
//   csr      @ 0x220000  : int[800000]          (3.2 MB)

__global__ __launch_bounds__(256) void zero_hist_kernel(int* __restrict__ hist) {
    int i = blockIdx.x * 256 + threadIdx.x;
    if (i < NNODES) hist[i] = 0;
}

__global__ __launch_bounds__(128) void table_kernel(
    const float* __restrict__ W1, const float* __restrict__ W2,
    float* __restrict__ tab)
{
    __shared__ float hs[100];
    const int i = blockIdx.x;
    const int t = threadIdx.x;
    const float r = (float)i * (RCUT / (float)(NT - 1));
    if (t < 100) {
        const float step = 2.0f / 9.0f, istep = 4.5f, cemb = 2.8234622f;
        float pre = 0.f;
        #pragma unroll
        for (int j = 0; j < NBASIS; ++j) {
            float dv = (r - (float)j * step) * istep;
            pre += expf(-dv * dv) * cemb * W1[j * 100 + t];
        }
        float z = pre * 0.316227766f;
        hs[t] = z / (1.0f + expf(-z));
    }
    __syncthreads();
    float acc = 0.f;
    for (int k = 0; k < 100; ++k) acc += hs[k] * W2[k * 128 + t];
    tab[i * 128 + t] = acc * 0.1f;
}

__global__ __launch_bounds__(256) void hist_kernel(
    const float* __restrict__ pos,
    const int* __restrict__ esrc, const int* __restrict__ edst,
    int* __restrict__ hist, unsigned long long* __restrict__ actbits)
{
    int e = blockIdx.x * 256 + threadIdx.x;
    bool act = false;
    int d = 0;
    if (e < NEDGES) {
        int s = esrc[e]; d = edst[e];
        float vx = pos[3*s]   - pos[3*d];
        float vy = pos[3*s+1] - pos[3*d+1];
        float vz = pos[3*s+2] - pos[3*d+2];
        act = (vx*vx + vy*vy + vz*vz) <= RCUT * RCUT;
    }
    unsigned long long mask = __ballot(act);
    if ((threadIdx.x & 63) == 0) actbits[e >> 6] = mask;
    if (act) atomicAdd(&hist[d], 1);
}

__global__ __launch_bounds__(256) void scanA_kernel(const int* __restrict__ hist,
                                                    int* __restrict__ bsums) {
    __shared__ int s[256];
    int i = blockIdx.x * 256 + threadIdx.x;
    int v = (i < NNODES) ? hist[i] : 0;
    s[threadIdx.x] = v;
    __syncthreads();
    for (int off = 128; off > 0; off >>= 1) {
        if (threadIdx.x < off) s[threadIdx.x] += s[threadIdx.x + off];
        __syncthreads();
    }
    if (threadIdx.x == 0) bsums[blockIdx.x] = s[0];
}

__global__ __launch_bounds__(256) void scanB_kernel(const int* __restrict__ bsums,
                                                    int* __restrict__ bscan) {
    __shared__ int s[256];
    int t = threadIdx.x;
    int v = (t < NCHUNK) ? bsums[t] : 0;
    s[t] = v;
    __syncthreads();
    for (int off = 1; off < 256; off <<= 1) {
        int u = (t >= off) ? s[t - off] : 0;
        __syncthreads();
        s[t] += u;
        __syncthreads();
    }
    if (t < NCHUNK) bscan[t] = s[t] - v;   // exclusive
}

__global__ __launch_bounds__(256) void scanC_kernel(
    const int* __restrict__ hist, const int* __restrict__ bscan,
    int* __restrict__ row_st, int* __restrict__ cursor)
{
    __shared__ int s[256];
    int i = blockIdx.x * 256 + threadIdx.x;
    int t = threadIdx.x;
    int v = (i < NNODES) ? hist[i] : 0;
    s[t] = v;
    __syncthreads();
    for (int off = 1; off < 256; off <<= 1) {
        int u = (t >= off) ? s[t - off] : 0;
        __syncthreads();
        s[t] += u;
        __syncthreads();
    }
    int excl = s[t] - v + bscan[blockIdx.x];
    if (i < NNODES) { row_st[i] = excl; cursor[i] = excl; }
    if (i == NNODES - 1) row_st[NNODES] = excl + v;
}

__global__ __launch_bounds__(256) void fill_kernel(
    const int* __restrict__ edst, const unsigned long long* __restrict__ actbits,
    int* __restrict__ cursor, int* __restrict__ csr)
{
    int e = blockIdx.x * 256 + threadIdx.x;
    if (e >= NEDGES) return;
    unsigned long long mask = actbits[e >> 6];
    if ((mask >> (e & 63)) & 1ull) {
        int slot = atomicAdd(&cursor[edst[e]], 1);
        csr[slot] = e;
    }
}

__global__ __launch_bounds__(256) void gather_kernel(
    const float* __restrict__ pos, const float* __restrict__ x,
    const float* __restrict__ tab,
    const int* __restrict__ esrc,
    const int* __restrict__ row_st, const int* __restrict__ csr,
    float* __restrict__ out)
{
    const int node = blockIdx.x;
    const int f = threadIdx.x;

    // feature decomposition
    int cat, uu, ii2 = 0;
    if (f < 32)       { cat = 0; uu = f; }
    else if (f < 64)  { cat = 1; uu = f - 32; }
    else if (f < 160) { int g = f - 64;  cat = 2; uu = g / 3; ii2 = g - 3 * uu; }
    else              { int g = f - 160; cat = 3; uu = g / 3; ii2 = g - 3 * uu; }
    int m  = (cat == 0) ? uu : (cat == 1) ? 96 + uu : (cat == 2) ? 32 + uu : 64 + uu;
    int xi = (cat == 0 || cat == 2) ? uu : 32 + 3 * uu + ((cat == 3) ? ii2 : 0);

    const int beg = row_st[node], end = row_st[node + 1];
    const float pdx = pos[3*node], pdy = pos[3*node+1], pdz = pos[3*node+2];
    const float SQRT3 = 1.7320508075688772f;
    const float iscale = (float)(NT - 1) / RCUT;

    float acc = 0.f;
    for (int k = beg; k < end; ++k) {
        int e = csr[k];
        int s = esrc[e];
        float vx = pos[3*s] - pdx, vy = pos[3*s+1] - pdy, vz = pos[3*s+2] - pdz;
        float r = sqrtf(vx*vx + vy*vy + vz*vz + 1e-12f);
        float inv = 1.0f / r;
        float ux = vx * inv, uy = vy * inv, uz = vz * inv;
        float fidx = r * iscale;
        int ii = min((int)fidx, NT - 2);
        float fr = fidx - (float)ii;
        float a = tab[ii * 128 + m];
        float b = tab[ii * 128 + 128 + m];
        float w = a + (b - a) * fr;
        const float* xr = x + (size_t)s * 128;
        float val;
        if (cat == 0)      val = w * xr[xi];
        else if (cat == 1) val = w * (xr[xi] * ux + xr[xi+1] * uy + xr[xi+2] * uz);
        else if (cat == 2) val = w * xr[xi] * SQRT3 * ((ii2 == 0) ? ux : (ii2 == 1) ? uy : uz);
        else               val = w * xr[xi];
        acc += val;
    }
    out[(size_t)node * 256 + f] = acc * 0.25f;
}

extern "C" void kernel_launch(void* const* d_in, const int* in_sizes, int n_in,
                              void* d_out, int out_size, void* d_ws, size_t ws_size,
                              hipStream_t stream) {
    const float* pos = (const float*)d_in[0];
    const float* x   = (const float*)d_in[1];
    const float* W1  = (const float*)d_in[2];
    const float* W2  = (const float*)d_in[3];
    const int* esrc  = (const int*)d_in[4];
    const int* edst  = (const int*)d_in[5];
    float* out = (float*)d_out;

    char* wsb = (char*)d_ws;
    float* tab   = (float*)wsb;
    int* hist    = (int*)(wsb + 0x100000);
    int* row_st  = (int*)(wsb + 0x140000);
    int* cursor  = (int*)(wsb + 0x180000);
    int* bsums   = (int*)(wsb + 0x1C0000);
    int* bscan   = (int*)(wsb + 0x1C1000);
    unsigned long long* actbits = (unsigned long long*)(wsb + 0x200000);
    int* csr     = (int*)(wsb + 0x220000);

    zero_hist_kernel<<<NCHUNK, 256, 0, stream>>>(hist);
    table_kernel<<<NT, 128, 0, stream>>>(W1, W2, tab);
    hist_kernel<<<(NEDGES + 255) / 256, 256, 0, stream>>>(pos, esrc, edst, hist, actbits);
    scanA_kernel<<<NCHUNK, 256, 0, stream>>>(hist, bsums);
    scanB_kernel<<<1, 256, 0, stream>>>(bsums, bscan);
    scanC_kernel<<<NCHUNK, 256, 0, stream>>>(hist, bscan, row_st, cursor);
    fill_kernel<<<(NEDGES + 255) / 256, 256, 0, stream>>>(edst, actbits, cursor, csr);
    gather_kernel<<<NNODES, 256, 0, stream>>>(pos, x, tab, esrc, row_st, csr, out);
}

// Round 4
// 138.187 us; speedup vs baseline: 3.3625x; 1.2405x over previous
//
#include <hip/hip_runtime.h>
#include <math.h>

#define NNODES 50000
#define NEDGES 800000
#define NBASIS 10
#define NT 2048
#define RCUT 3.0f
#define NCHUNK 196   // ceil(50000/256)

// ws layout (bytes):
//   tab      @ 0x000000 : float[NT*128]          (1 MB)
//   tabP     @ 0x100000 : float2[(NT-1)*128]     (2 MB)
//   hist     @ 0x300000 : int[50000]
//   row_st   @ 0x340000 : int[50001]
//   cursor   @ 0x380000 : int[50000]
//   bsums    @ 0x3C0000 : int[256]
//   bscan    @ 0x3C1000 : int[256]
//   actbits  @ 0x3D0000 : ull[12500]
//   csrS     @ 0x400000 : int[800000]            (3.2 MB)
//   csrG     @ 0x800000 : float4[800000]         (12.8 MB)

__global__ __launch_bounds__(256) void zero_hist_kernel(int* __restrict__ hist) {
    int i = blockIdx.x * 256 + threadIdx.x;
    if (i < NNODES) hist[i] = 0;
}

__global__ __launch_bounds__(128) void table_kernel(
    const float* __restrict__ W1, const float* __restrict__ W2,
    float* __restrict__ tab)
{
    __shared__ float hs[100];
    const int i = blockIdx.x;
    const int t = threadIdx.x;
    const float r = (float)i * (RCUT / (float)(NT - 1));
    if (t < 100) {
        const float step = 2.0f / 9.0f, istep = 4.5f, cemb = 2.8234622f;
        float pre = 0.f;
        #pragma unroll
        for (int j = 0; j < NBASIS; ++j) {
            float dv = (r - (float)j * step) * istep;
            pre += expf(-dv * dv) * cemb * W1[j * 100 + t];
        }
        float z = pre * 0.316227766f;
        hs[t] = z / (1.0f + expf(-z));
    }
    __syncthreads();
    float acc = 0.f;
    for (int k = 0; k < 100; ++k) acc += hs[k] * W2[k * 128 + t];
    // fold /sqrt(100), /sqrt(16), and sqrt(3) for cat-2 columns (m in [32,64))
    float sc = 0.1f * 0.25f;
    if (t >= 32 && t < 64) sc *= 1.7320508075688772f;
    tab[i * 128 + t] = acc * sc;
}

// pair rows: tabP[i*256 + 2m+sel] = tab[(i+sel)*128 + m]
__global__ __launch_bounds__(256) void pack_kernel(
    const float* __restrict__ tab, float* __restrict__ tabP)
{
    int i = blockIdx.x;            // 0..NT-2
    int t = threadIdx.x;           // 0..255
    tabP[i * 256 + t] = tab[(i + (t & 1)) * 128 + (t >> 1)];
}

__global__ __launch_bounds__(256) void hist_kernel(
    const float* __restrict__ pos,
    const int* __restrict__ esrc, const int* __restrict__ edst,
    int* __restrict__ hist, unsigned long long* __restrict__ actbits)
{
    int e = blockIdx.x * 256 + threadIdx.x;
    bool act = false;
    int d = 0;
    if (e < NEDGES) {
        int s = esrc[e]; d = edst[e];
        float vx = pos[3*s]   - pos[3*d];
        float vy = pos[3*s+1] - pos[3*d+1];
        float vz = pos[3*s+2] - pos[3*d+2];
        act = (vx*vx + vy*vy + vz*vz) <= RCUT * RCUT;
    }
    unsigned long long mask = __ballot(act);
    if ((threadIdx.x & 63) == 0) actbits[e >> 6] = mask;
    if (act) atomicAdd(&hist[d], 1);
}

__global__ __launch_bounds__(256) void scanA_kernel(const int* __restrict__ hist,
                                                    int* __restrict__ bsums) {
    __shared__ int s[256];
    int i = blockIdx.x * 256 + threadIdx.x;
    int v = (i < NNODES) ? hist[i] : 0;
    s[threadIdx.x] = v;
    __syncthreads();
    for (int off = 128; off > 0; off >>= 1) {
        if (threadIdx.x < off) s[threadIdx.x] += s[threadIdx.x + off];
        __syncthreads();
    }
    if (threadIdx.x == 0) bsums[blockIdx.x] = s[0];
}

__global__ __launch_bounds__(256) void scanB_kernel(const int* __restrict__ bsums,
                                                    int* __restrict__ bscan) {
    __shared__ int s[256];
    int t = threadIdx.x;
    int v = (t < NCHUNK) ? bsums[t] : 0;
    s[t] = v;
    __syncthreads();
    for (int off = 1; off < 256; off <<= 1) {
        int u = (t >= off) ? s[t - off] : 0;
        __syncthreads();
        s[t] += u;
        __syncthreads();
    }
    if (t < NCHUNK) bscan[t] = s[t] - v;   // exclusive
}

__global__ __launch_bounds__(256) void scanC_kernel(
    const int* __restrict__ hist, const int* __restrict__ bscan,
    int* __restrict__ row_st, int* __restrict__ cursor)
{
    __shared__ int s[256];
    int i = blockIdx.x * 256 + threadIdx.x;
    int t = threadIdx.x;
    int v = (i < NNODES) ? hist[i] : 0;
    s[t] = v;
    __syncthreads();
    for (int off = 1; off < 256; off <<= 1) {
        int u = (t >= off) ? s[t - off] : 0;
        __syncthreads();
        s[t] += u;
        __syncthreads();
    }
    int excl = s[t] - v + bscan[blockIdx.x];
    if (i < NNODES) { row_st[i] = excl; cursor[i] = excl; }
    if (i == NNODES - 1) row_st[NNODES] = excl + v;
}

// fill CSR slots AND precompute per-edge geometry {ux,uy,uz,fidx}, src
__global__ __launch_bounds__(256) void fill_kernel(
    const float* __restrict__ pos,
    const int* __restrict__ esrc, const int* __restrict__ edst,
    const unsigned long long* __restrict__ actbits,
    int* __restrict__ cursor, float4* __restrict__ csrG, int* __restrict__ csrS)
{
    int e = blockIdx.x * 256 + threadIdx.x;
    if (e >= NEDGES) return;
    if (!((actbits[e >> 6] >> (e & 63)) & 1ull)) return;
    int s = esrc[e], d = edst[e];
    float vx = pos[3*s]   - pos[3*d];
    float vy = pos[3*s+1] - pos[3*d+1];
    float vz = pos[3*s+2] - pos[3*d+2];
    float r = sqrtf(vx*vx + vy*vy + vz*vz + 1e-12f);
    float inv = 1.0f / r;
    const float iscale = (float)(NT - 1) / RCUT;
    int slot = atomicAdd(&cursor[d], 1);
    csrG[slot] = make_float4(vx * inv, vy * inv, vz * inv, r * iscale);
    csrS[slot] = s;
}

__global__ __launch_bounds__(256) void gather_kernel(
    const float* __restrict__ x, const float2* __restrict__ tabP,
    const int* __restrict__ row_st,
    const float4* __restrict__ csrG, const int* __restrict__ csrS,
    float* __restrict__ out)
{
    const int node = blockIdx.x;
    const int f = threadIdx.x;

    int cat, uu, ii2 = 0;
    if (f < 32)       { cat = 0; uu = f; }
    else if (f < 64)  { cat = 1; uu = f - 32; }
    else if (f < 160) { int g = f - 64;  cat = 2; uu = g / 3; ii2 = g - 3 * uu; }
    else              { int g = f - 160; cat = 3; uu = g / 3; ii2 = g - 3 * uu; }
    const int m  = (cat == 0) ? uu : (cat == 1) ? 96 + uu : (cat == 2) ? 32 + uu : 64 + uu;
    const int xi = (cat == 0 || cat == 2) ? uu : 32 + 3 * uu + ((cat == 3) ? ii2 : 0);

    const int beg = row_st[node], end = row_st[node + 1];

    float acc = 0.f;
    float4 g = make_float4(0.f, 0.f, 0.f, 0.f);
    int s = 0;
    if (beg < end) { g = csrG[beg]; s = csrS[beg]; }
    for (int k = beg; k < end; ++k) {
        float4 gc = g; int sc = s;
        if (k + 1 < end) { g = csrG[k + 1]; s = csrS[k + 1]; }  // prefetch next edge
        int ii = min((int)gc.w, NT - 2);
        float fr = gc.w - (float)ii;
        float2 ab = tabP[ii * 128 + m];
        float w = ab.x + (ab.y - ab.x) * fr;
        const float* xr = x + (size_t)sc * 128;
        float val;
        if (cat == 0)      val = w * xr[xi];
        else if (cat == 1) val = w * (xr[xi] * gc.x + xr[xi+1] * gc.y + xr[xi+2] * gc.z);
        else if (cat == 2) val = w * xr[xi] * ((ii2 == 0) ? gc.x : (ii2 == 1) ? gc.y : gc.z);
        else               val = w * xr[xi];
        acc += val;
    }
    out[(size_t)node * 256 + f] = acc;
}

extern "C" void kernel_launch(void* const* d_in, const int* in_sizes, int n_in,
                              void* d_out, int out_size, void* d_ws, size_t ws_size,
                              hipStream_t stream) {
    const float* pos = (const float*)d_in[0];
    const float* x   = (const float*)d_in[1];
    const float* W1  = (const float*)d_in[2];
    const float* W2  = (const float*)d_in[3];
    const int* esrc  = (const int*)d_in[4];
    const int* edst  = (const int*)d_in[5];
    float* out = (float*)d_out;

    char* wsb = (char*)d_ws;
    float* tab   = (float*)wsb;
    float* tabP  = (float*)(wsb + 0x100000);
    int* hist    = (int*)(wsb + 0x300000);
    int* row_st  = (int*)(wsb + 0x340000);
    int* cursor  = (int*)(wsb + 0x380000);
    int* bsums   = (int*)(wsb + 0x3C0000);
    int* bscan   = (int*)(wsb + 0x3C1000);
    unsigned long long* actbits = (unsigned long long*)(wsb + 0x3D0000);
    int* csrS    = (int*)(wsb + 0x400000);
    float4* csrG = (float4*)(wsb + 0x800000);

    zero_hist_kernel<<<NCHUNK, 256, 0, stream>>>(hist);
    table_kernel<<<NT, 128, 0, stream>>>(W1, W2, tab);
    pack_kernel<<<NT - 1, 256, 0, stream>>>(tab, tabP);
    hist_kernel<<<(NEDGES + 255) / 256, 256, 0, stream>>>(pos, esrc, edst, hist, actbits);
    scanA_kernel<<<NCHUNK, 256, 0, stream>>>(hist, bsums);
    scanB_kernel<<<1, 256, 0, stream>>>(bsums, bscan);
    scanC_kernel<<<NCHUNK, 256, 0, stream>>>(hist, bscan, row_st, cursor);
    fill_kernel<<<(NEDGES + 255) / 256, 256, 0, stream>>>(pos, esrc, edst, actbits, cursor, csrG, csrS);
    gather_kernel<<<NNODES, 256, 0, stream>>>(x, (const float2*)tabP, row_st, csrG, csrS, out);
}

// Round 5
// 119.206 us; speedup vs baseline: 3.8979x; 1.1592x over previous
//
#include <hip/hip_runtime.h>
#include <math.h>

#define NNODES 50000
#define NEDGES 800000
#define NBASIS 10
#define NT 2048
#define RCUT 3.0f
#define NCHUNK 196   // ceil(50000/256)

// ws layout (bytes):
//   tab      @ 0x000000 : float[NT*128]          (1 MB)
//   tabP     @ 0x100000 : float2[(NT-1)*128]     (2 MB)
//   hist     @ 0x300000 : int[50000]
//   row_st   @ 0x340000 : int[50001]
//   cursor   @ 0x380000 : int[50000]
//   bsums    @ 0x3C0000 : int[256]
//   bscan    @ 0x3C1000 : int[256]
//   actbits  @ 0x3D0000 : ull[12500]
//   csrS     @ 0x400000 : int[800000]            (3.2 MB)
//   csrG     @ 0x800000 : float4[800000]         (12.8 MB)

__global__ __launch_bounds__(128) void table_kernel(
    const float* __restrict__ W1, const float* __restrict__ W2,
    float* __restrict__ tab, int* __restrict__ hist)
{
    // fold hist zeroing into this 262144-thread grid
    int gid = blockIdx.x * 128 + threadIdx.x;
    if (gid < NNODES) hist[gid] = 0;

    __shared__ float hs[100];
    const int i = blockIdx.x;
    const int t = threadIdx.x;
    const float r = (float)i * (RCUT / (float)(NT - 1));
    if (t < 100) {
        const float step = 2.0f / 9.0f, istep = 4.5f, cemb = 2.8234622f;
        float pre = 0.f;
        #pragma unroll
        for (int j = 0; j < NBASIS; ++j) {
            float dv = (r - (float)j * step) * istep;
            pre += expf(-dv * dv) * cemb * W1[j * 100 + t];
        }
        float z = pre * 0.316227766f;
        hs[t] = z / (1.0f + expf(-z));
    }
    __syncthreads();
    float acc = 0.f;
    for (int k = 0; k < 100; ++k) acc += hs[k] * W2[k * 128 + t];
    // fold /sqrt(100), /sqrt(16), and sqrt(3) for cat-2 columns (m in [32,64))
    float sc = 0.1f * 0.25f;
    if (t >= 32 && t < 64) sc *= 1.7320508075688772f;
    tab[i * 128 + t] = acc * sc;
}

// pair rows: tabP[i*256 + 2m+sel] = tab[(i+sel)*128 + m]
__global__ __launch_bounds__(256) void pack_kernel(
    const float* __restrict__ tab, float* __restrict__ tabP)
{
    int i = blockIdx.x;            // 0..NT-2
    int t = threadIdx.x;           // 0..255
    tabP[i * 256 + t] = tab[(i + (t & 1)) * 128 + (t >> 1)];
}

__global__ __launch_bounds__(256) void hist_kernel(
    const float* __restrict__ pos,
    const int* __restrict__ esrc, const int* __restrict__ edst,
    int* __restrict__ hist, unsigned long long* __restrict__ actbits)
{
    int e = blockIdx.x * 256 + threadIdx.x;
    bool act = false;
    int d = 0;
    if (e < NEDGES) {
        int s = esrc[e]; d = edst[e];
        float vx = pos[3*s]   - pos[3*d];
        float vy = pos[3*s+1] - pos[3*d+1];
        float vz = pos[3*s+2] - pos[3*d+2];
        act = (vx*vx + vy*vy + vz*vz) <= RCUT * RCUT;
    }
    unsigned long long mask = __ballot(act);
    if ((threadIdx.x & 63) == 0) actbits[e >> 6] = mask;
    if (act) atomicAdd(&hist[d], 1);
}

__global__ __launch_bounds__(256) void scanA_kernel(const int* __restrict__ hist,
                                                    int* __restrict__ bsums) {
    __shared__ int s[256];
    int i = blockIdx.x * 256 + threadIdx.x;
    int v = (i < NNODES) ? hist[i] : 0;
    s[threadIdx.x] = v;
    __syncthreads();
    for (int off = 128; off > 0; off >>= 1) {
        if (threadIdx.x < off) s[threadIdx.x] += s[threadIdx.x + off];
        __syncthreads();
    }
    if (threadIdx.x == 0) bsums[blockIdx.x] = s[0];
}

__global__ __launch_bounds__(256) void scanB_kernel(const int* __restrict__ bsums,
                                                    int* __restrict__ bscan) {
    __shared__ int s[256];
    int t = threadIdx.x;
    int v = (t < NCHUNK) ? bsums[t] : 0;
    s[t] = v;
    __syncthreads();
    for (int off = 1; off < 256; off <<= 1) {
        int u = (t >= off) ? s[t - off] : 0;
        __syncthreads();
        s[t] += u;
        __syncthreads();
    }
    if (t < NCHUNK) bscan[t] = s[t] - v;   // exclusive
}

__global__ __launch_bounds__(256) void scanC_kernel(
    const int* __restrict__ hist, const int* __restrict__ bscan,
    int* __restrict__ row_st, int* __restrict__ cursor)
{
    __shared__ int s[256];
    int i = blockIdx.x * 256 + threadIdx.x;
    int t = threadIdx.x;
    int v = (i < NNODES) ? hist[i] : 0;
    s[t] = v;
    __syncthreads();
    for (int off = 1; off < 256; off <<= 1) {
        int u = (t >= off) ? s[t - off] : 0;
        __syncthreads();
        s[t] += u;
        __syncthreads();
    }
    int excl = s[t] - v + bscan[blockIdx.x];
    if (i < NNODES) { row_st[i] = excl; cursor[i] = excl; }
    if (i == NNODES - 1) row_st[NNODES] = excl + v;
}

// fill CSR slots AND precompute per-edge geometry {ux,uy,uz,fidx}, src
__global__ __launch_bounds__(256) void fill_kernel(
    const float* __restrict__ pos,
    const int* __restrict__ esrc, const int* __restrict__ edst,
    const unsigned long long* __restrict__ actbits,
    int* __restrict__ cursor, float4* __restrict__ csrG, int* __restrict__ csrS)
{
    int e = blockIdx.x * 256 + threadIdx.x;
    if (e >= NEDGES) return;
    if (!((actbits[e >> 6] >> (e & 63)) & 1ull)) return;
    int s = esrc[e], d = edst[e];
    float vx = pos[3*s]   - pos[3*d];
    float vy = pos[3*s+1] - pos[3*d+1];
    float vz = pos[3*s+2] - pos[3*d+2];
    float r = sqrtf(vx*vx + vy*vy + vz*vz + 1e-12f);
    float inv = 1.0f / r;
    const float iscale = (float)(NT - 1) / RCUT;
    int slot = atomicAdd(&cursor[d], 1);
    csrG[slot] = make_float4(vx * inv, vy * inv, vz * inv, r * iscale);
    csrS[slot] = s;
}

// wave-per-node gather: block = 4 independent waves, lane owns 4 features
__global__ __launch_bounds__(256) void gather_kernel(
    const float* __restrict__ x, const float2* __restrict__ tabP,
    const int* __restrict__ row_st,
    const float4* __restrict__ csrG, const int* __restrict__ csrS,
    float* __restrict__ out)
{
    const int lane = threadIdx.x & 63;
    const int node = blockIdx.x * 4 + (threadIdx.x >> 6);
    const bool lo = lane < 32;

    // j0: f = lane        -> cat0 (lo) / cat1 (hi)
    const int m0  = lo ? lane : 64 + lane;          // cat1: 96 + (lane-32)
    const int xi0 = lo ? lane : 3 * lane - 64;      // cat1: 32 + 3*(lane-32)
    // j1: f = 64 + lane   -> cat2, g = lane
    const int uu1 = lane / 3;
    const int m1 = 32 + uu1, xi1 = uu1, c1 = lane - 3 * uu1;
    // j2: f = 128 + lane  -> cat2 (lo, g = 64+lane) / cat3 (hi, g = lane-32)
    const int uu2a = (64 + lane) / 3;
    const int m2  = lo ? 32 + uu2a : 64 + (lane - 32) / 3;
    const int xi2 = lo ? uu2a : lane;               // cat3: xi = 32+g = lane
    const int c2  = (64 + lane) - 3 * uu2a;         // used only when lo
    // j3: f = 192 + lane  -> cat3, g = 32 + lane
    const int uu3 = (32 + lane) / 3;
    const int m3 = 64 + uu3, xi3 = 64 + lane;       // xi = 32 + g

    const int beg = row_st[node], end = row_st[node + 1];
    float a0 = 0.f, a1 = 0.f, a2 = 0.f, a3 = 0.f;

    float4 g = make_float4(0.f, 0.f, 0.f, 0.f);
    int s = 0;
    if (beg < end) { g = csrG[beg]; s = csrS[beg]; }
    for (int k = beg; k < end; ++k) {
        const float4 gc = g; const int sc = s;
        if (k + 1 < end) { g = csrG[k + 1]; s = csrS[k + 1]; }   // 1-ahead prefetch
        const int ii = min((int)gc.w, NT - 2);
        const float fr = gc.w - (float)ii;
        const float2* tp = tabP + (size_t)ii * 128;
        const float2 p0 = tp[m0], p1 = tp[m1], p2 = tp[m2], p3 = tp[m3];
        const float* xr = x + (size_t)sc * 128;
        const float w0 = p0.x + (p0.y - p0.x) * fr;
        const float w1 = p1.x + (p1.y - p1.x) * fr;
        const float w2 = p2.x + (p2.y - p2.x) * fr;
        const float w3 = p3.x + (p3.y - p3.x) * fr;
        const float u1 = (c1 == 0) ? gc.x : (c1 == 1) ? gc.y : gc.z;
        if (lo) {
            a0 += w0 * xr[xi0];
            const float u2 = (c2 == 0) ? gc.x : (c2 == 1) ? gc.y : gc.z;
            a2 += w2 * xr[xi2] * u2;
        } else {
            a0 += w0 * (xr[xi0] * gc.x + xr[xi0 + 1] * gc.y + xr[xi0 + 2] * gc.z);
            a2 += w2 * xr[xi2];
        }
        a1 += w1 * xr[xi1] * u1;
        a3 += w3 * xr[xi3];
    }
    float* orow = out + (size_t)node * 256;
    orow[lane]        = a0;
    orow[64 + lane]   = a1;
    orow[128 + lane]  = a2;
    orow[192 + lane]  = a3;
}

extern "C" void kernel_launch(void* const* d_in, const int* in_sizes, int n_in,
                              void* d_out, int out_size, void* d_ws, size_t ws_size,
                              hipStream_t stream) {
    const float* pos = (const float*)d_in[0];
    const float* x   = (const float*)d_in[1];
    const float* W1  = (const float*)d_in[2];
    const float* W2  = (const float*)d_in[3];
    const int* esrc  = (const int*)d_in[4];
    const int* edst  = (const int*)d_in[5];
    float* out = (float*)d_out;

    char* wsb = (char*)d_ws;
    float* tab   = (float*)wsb;
    float* tabP  = (float*)(wsb + 0x100000);
    int* hist    = (int*)(wsb + 0x300000);
    int* row_st  = (int*)(wsb + 0x340000);
    int* cursor  = (int*)(wsb + 0x380000);
    int* bsums   = (int*)(wsb + 0x3C0000);
    int* bscan   = (int*)(wsb + 0x3C1000);
    unsigned long long* actbits = (unsigned long long*)(wsb + 0x3D0000);
    int* csrS    = (int*)(wsb + 0x400000);
    float4* csrG = (float4*)(wsb + 0x800000);

    table_kernel<<<NT, 128, 0, stream>>>(W1, W2, tab, hist);
    pack_kernel<<<NT - 1, 256, 0, stream>>>(tab, tabP);
    hist_kernel<<<(NEDGES + 255) / 256, 256, 0, stream>>>(pos, esrc, edst, hist, actbits);
    scanA_kernel<<<NCHUNK, 256, 0, stream>>>(hist, bsums);
    scanB_kernel<<<1, 256, 0, stream>>>(bsums, bscan);
    scanC_kernel<<<NCHUNK, 256, 0, stream>>>(hist, bscan, row_st, cursor);
    fill_kernel<<<(NEDGES + 255) / 256, 256, 0, stream>>>(pos, esrc, edst, actbits, cursor, csrG, csrS);
    gather_kernel<<<(NNODES + 3) / 4, 256, 0, stream>>>(x, (const float2*)tabP, row_st, csrG, csrS, out);
}